// Round 1
// baseline (313.508 us; speedup 1.0000x reference)
//
#include <hip/hip_runtime.h>
#include <math.h>

// Problem constants
#define WSZ 8
#define NT 16
#define NR 8
#define PD 32
#define HG 48
#define WG 48
#define NB 8
#define CH 96
#define HW 384
#define CCH 16                 // channels per staged chunk
#define NCHUNK (CH / CCH)      // 6
#define S8 0.70710678118654752f

static __device__ const float CT16[16] = {
    1.0f, 0.9238795325112867f, 0.7071067811865476f, 0.3826834323650898f,
    0.0f, -0.3826834323650898f, -0.7071067811865476f, -0.9238795325112867f,
    -1.0f, -0.9238795325112867f, -0.7071067811865476f, -0.3826834323650898f,
    0.0f, 0.3826834323650898f, 0.7071067811865476f, 0.9238795325112867f};
static __device__ const float ST16[16] = {
    0.0f, 0.3826834323650898f, 0.7071067811865476f, 0.9238795325112867f,
    1.0f, 0.9238795325112867f, 0.7071067811865476f, 0.3826834323650898f,
    0.0f, -0.3826834323650898f, -0.7071067811865476f, -0.9238795325112867f,
    -1.0f, -0.9238795325112867f, -0.7071067811865476f, -0.3826834323650898f};

#define MAGR(x_) log1pf(0.125f * fabsf(x_))
#define MAGC(re_, im_) log1pf(0.125f * sqrtf((re_) * (re_) + (im_) * (im_)))

__global__ __launch_bounds__(256, 2) void lpp_kernel(
    const float* __restrict__ x, const float* __restrict__ Wp,
    const float* __restrict__ bp, float* __restrict__ out) {
  // Region A: 256 planes x 64 floats (64KB). During projection: chunk buffer
  // (first 8192 floats). After: feat/mag planes (XOR-swizzled).
  __shared__ float ldsA[256 * 64];
  // Region B: Wt (96x32) during projection; tables + dist/conf after.
  __shared__ float ldsB[CH * PD];

  const int tid = threadIdx.x;
  const int gid = blockIdx.x;
  const int wxg = gid % 6;             // group of 8 windows along W
  const int hy = (gid / 6) % HG;       // window row
  const int b = gid / (6 * HG);        // batch
  const int x0p = wxg * 64;
  const int y0p = hy * WSZ;
  const int pg = tid & 63;             // column within strip
  const int og = tid >> 6;             // output-channel group (wave id)

  // ---- stage W transposed into ldsB: Wt[c][o] = W[o][c] ----
  for (int e = 0; e < (CH * PD) / 256; ++e) {
    int j = tid + 256 * e;
    int o = j / CH;
    int c = j - o * CH;
    ldsB[c * PD + o] = Wp[j];
  }

  float bias[8];
#pragma unroll
  for (int oo = 0; oo < 8; ++oo) bias[oo] = bp[og * 8 + oo];

  float acc[8][8];
#pragma unroll
  for (int oo = 0; oo < 8; ++oo)
#pragma unroll
    for (int k = 0; k < 8; ++k) acc[oo][k] = bias[oo];

  // ---- projection: feat[o][row][col] = sum_c W[o][c]*x[c,row,col] + b[o] ----
  const size_t xbase = (size_t)b * CH * (HW * HW);
  float4 vv[8];
#pragma unroll
  for (int i = 0; i < 8; ++i) {  // prefetch chunk 0
    int f = tid + 256 * i;
    int c = f >> 7, r = (f >> 4) & 7, c4 = f & 15;
    vv[i] = *(const float4*)(x + xbase + (size_t)c * (HW * HW) +
                             (size_t)(y0p + r) * HW + x0p + c4 * 4);
  }
  for (int ch = 0; ch < NCHUNK; ++ch) {
    if (ch) __syncthreads();  // prev chunk fully consumed
#pragma unroll
    for (int i = 0; i < 8; ++i) {
      int f = tid + 256 * i;
      *(float4*)&ldsA[f * 4] = vv[i];
    }
    if (ch + 1 < NCHUNK) {  // prefetch next chunk into regs (hides HBM latency)
      int cb = (ch + 1) * CCH;
#pragma unroll
      for (int i = 0; i < 8; ++i) {
        int f = tid + 256 * i;
        int c = f >> 7, r = (f >> 4) & 7, c4 = f & 15;
        vv[i] = *(const float4*)(x + xbase + (size_t)(cb + c) * (HW * HW) +
                                 (size_t)(y0p + r) * HW + x0p + c4 * 4);
      }
    }
    __syncthreads();  // chunk ready in LDS
    const float* wtp = &ldsB[(ch * CCH) * PD + og * 8];
#pragma unroll 4
    for (int c = 0; c < CCH; ++c) {
      float xv[8];
#pragma unroll
      for (int k = 0; k < 8; ++k) xv[k] = ldsA[c * 512 + k * 64 + pg];
      float wv[8];
      *(float4*)&wv[0] = *(const float4*)(wtp + c * PD);
      *(float4*)&wv[4] = *(const float4*)(wtp + c * PD + 4);
#pragma unroll
      for (int oo = 0; oo < 8; ++oo)
#pragma unroll
        for (int k = 0; k < 8; ++k)
          acc[oo][k] = fmaf(wv[oo], xv[k], acc[oo][k]);
    }
  }
  __syncthreads();  // last chunk consumed; regions A and B are free

  // ---- scatter feat into per-plane LDS (XOR swizzle vs plane&31) ----
  {
    int win = pg >> 3, col = pg & 7;
#pragma unroll
    for (int oo = 0; oo < 8; ++oo) {
      int p = win * PD + og * 8 + oo;
      int pbase = p * 64, sx = p & 31;
#pragma unroll
      for (int k = 0; k < 8; ++k) ldsA[pbase + ((k * 8 + col) ^ sx)] = acc[oo][k];
    }
  }
  // ---- build polar bilinear tables (reuses ldsB) ----
  if (tid < 128) {
    int r = tid >> 4, t = tid & 15;
    float rad = (float)r / 7.0f;
    float px = (rad * CT16[t] + 1.0f) * 3.5f;
    float py = (rad * ST16[t] + 1.0f) * 3.5f;
    float xf = floorf(px), yf = floorf(py);
    float wx = px - xf, wy = py - yf;
    int ix = (int)xf, iy = (int)yf;
    int xi0 = min(max(ix, 0), 7), xi1 = min(max(ix + 1, 0), 7);
    int yi0 = min(max(iy, 0), 7), yi1 = min(max(iy + 1, 0), 7);
    bool vx0 = (ix >= 0) && (ix < 8), vx1 = (ix + 1 >= 0) && (ix + 1 < 8);
    bool vy0 = (iy >= 0) && (iy < 8), vy1 = (iy + 1 >= 0) && (iy + 1 < 8);
    int4 I;
    float4 Wv;
    I.x = yi0 * 8 + xi0; Wv.x = (vx0 && vy0) ? (1.f - wx) * (1.f - wy) : 0.f;
    I.y = yi0 * 8 + xi1; Wv.y = (vx1 && vy0) ? wx * (1.f - wy) : 0.f;
    I.z = yi1 * 8 + xi0; Wv.z = (vx0 && vy1) ? (1.f - wx) * wy : 0.f;
    I.w = yi1 * 8 + xi1; Wv.w = (vx1 && vy1) ? wx * wy : 0.f;
    *(int4*)&ldsB[tid * 4] = I;
    *(float4*)&ldsB[512 + tid * 4] = Wv;
  }
  __syncthreads();

  // ---- per-thread 8x8 real 2D FFT -> shifted log-magnitude (own plane) ----
  const int xr = tid & 31;
  float* magp = &ldsA[tid * 64];
  float rr[8][8];  // per row k: {R0, R4, R1r, R1i, R2r, R2i, R3r, R3i}
#pragma unroll
  for (int k = 0; k < 8; ++k) {
    float v[8];
#pragma unroll
    for (int j = 0; j < 8; ++j) v[j] = magp[(k * 8 + j) ^ xr];
    float a0 = v[0] + v[4], a1 = v[0] - v[4], a2 = v[2] + v[6], a3 = v[2] - v[6];
    float b0 = v[1] + v[5], b1 = v[1] - v[5], b2 = v[3] + v[7], b3 = v[3] - v[7];
    float e0 = a0 + a2, e2 = a0 - a2, o0 = b0 + b2, o2 = b0 - b2;
    float t1 = S8 * (b1 - b3), t2 = S8 * (b1 + b3);
    rr[k][0] = e0 + o0; rr[k][1] = e0 - o0;
    rr[k][2] = a1 + t1; rr[k][3] = -a3 - t2;
    rr[k][4] = e2;      rr[k][5] = -o2;
    rr[k][6] = a1 - t1; rr[k][7] = a3 - t2;
  }
  float mg0[5], mg4[5], mg1[8], mg2[8], mg3[8];
#define REALCOL(SLOT, OUT)                                                     \
  {                                                                            \
    float a0 = rr[0][SLOT] + rr[4][SLOT], a1 = rr[0][SLOT] - rr[4][SLOT];      \
    float a2 = rr[2][SLOT] + rr[6][SLOT], a3 = rr[2][SLOT] - rr[6][SLOT];      \
    float b0 = rr[1][SLOT] + rr[5][SLOT], b1 = rr[1][SLOT] - rr[5][SLOT];      \
    float b2 = rr[3][SLOT] + rr[7][SLOT], b3 = rr[3][SLOT] - rr[7][SLOT];      \
    float e0 = a0 + a2, e2 = a0 - a2, o0 = b0 + b2, o2 = b0 - b2;              \
    float t1 = S8 * (b1 - b3), t2 = S8 * (b1 + b3);                            \
    OUT[0] = MAGR(e0 + o0); OUT[4] = MAGR(e0 - o0);                            \
    OUT[1] = MAGC(a1 + t1, -a3 - t2);                                          \
    OUT[2] = MAGC(e2, -o2);                                                    \
    OUT[3] = MAGC(a1 - t1, a3 - t2);                                           \
  }
#define CPLXCOL(SR, SI, OUT)                                                   \
  {                                                                            \
    float t0r = rr[0][SR] + rr[4][SR], t0i = rr[0][SI] + rr[4][SI];            \
    float t1r = rr[0][SR] - rr[4][SR], t1i = rr[0][SI] - rr[4][SI];            \
    float t2r = rr[2][SR] + rr[6][SR], t2i = rr[2][SI] + rr[6][SI];            \
    float t3r = rr[2][SR] - rr[6][SR], t3i = rr[2][SI] - rr[6][SI];            \
    float E0r = t0r + t2r, E0i = t0i + t2i, E2r = t0r - t2r, E2i = t0i - t2i;  \
    float E1r = t1r + t3i, E1i = t1i - t3r, E3r = t1r - t3i, E3i = t1i + t3r;  \
    float u0r = rr[1][SR] + rr[5][SR], u0i = rr[1][SI] + rr[5][SI];            \
    float u1r = rr[1][SR] - rr[5][SR], u1i = rr[1][SI] - rr[5][SI];            \
    float u2r = rr[3][SR] + rr[7][SR], u2i = rr[3][SI] + rr[7][SI];            \
    float u3r = rr[3][SR] - rr[7][SR], u3i = rr[3][SI] - rr[7][SI];            \
    float O0r = u0r + u2r, O0i = u0i + u2i, O2r = u0r - u2r, O2i = u0i - u2i;  \
    float O1r = u1r + u3i, O1i = u1i - u3r, O3r = u1r - u3i, O3i = u1i + u3r;  \
    float W1r = S8 * (O1r + O1i), W1i = S8 * (O1i - O1r);                      \
    float W2r = O2i, W2i = -O2r;                                               \
    float W3r = S8 * (O3i - O3r), W3i = -S8 * (O3r + O3i);                     \
    OUT[0] = MAGC(E0r + O0r, E0i + O0i); OUT[4] = MAGC(E0r - O0r, E0i - O0i);  \
    OUT[1] = MAGC(E1r + W1r, E1i + W1i); OUT[5] = MAGC(E1r - W1r, E1i - W1i);  \
    OUT[2] = MAGC(E2r + W2r, E2i + W2i); OUT[6] = MAGC(E2r - W2r, E2i - W2i);  \
    OUT[3] = MAGC(E3r + W3r, E3i + W3i); OUT[7] = MAGC(E3r - W3r, E3i - W3i);  \
  }
  REALCOL(0, mg0)
  REALCOL(1, mg4)
  CPLXCOL(2, 3, mg1)
  CPLXCOL(4, 5, mg2)
  CPLXCOL(6, 7, mg3)
  // expand (hermitian) + fftshift, write back into own plane
#pragma unroll
  for (int up = 0; up < 8; ++up) {
#pragma unroll
    for (int vp = 0; vp < 8; ++vp) {
      const int u = (up + 4) & 7, v = (vp + 4) & 7;
      float m;
      if (v == 0)      m = mg0[(u <= 4) ? u : (8 - u)];
      else if (v == 4) m = mg4[(u <= 4) ? u : (8 - u)];
      else if (v == 1) m = mg1[u];
      else if (v == 2) m = mg2[u];
      else if (v == 3) m = mg3[u];
      else { const int uu = (8 - u) & 7;
             m = (v == 5) ? mg3[uu] : (v == 6) ? mg2[uu] : mg1[uu]; }
      magp[(up * 8 + vp) ^ xr] = m;
    }
  }

  // ---- polar bilinear sample, sum over radii ----
  float psum[16];
#pragma unroll
  for (int t = 0; t < 16; ++t) psum[t] = 0.f;
  for (int r = 0; r < 8; ++r) {
#pragma unroll
    for (int t = 0; t < 16; ++t) {
      int p = r * 16 + t;
      int4 I = *(const int4*)&ldsB[p * 4];
      float4 Wv = *(const float4*)&ldsB[512 + p * 4];
      psum[t] += Wv.x * magp[I.x ^ xr] + Wv.y * magp[I.y ^ xr] +
                 Wv.z * magp[I.z ^ xr] + Wv.w * magp[I.w ^ xr];
    }
  }

  // ---- reduce over 32 channels (half-wave butterfly) ----
#pragma unroll
  for (int m = 1; m < 32; m <<= 1)
#pragma unroll
    for (int t = 0; t < 16; ++t) psum[t] += __shfl_xor(psum[t], m, 64);

  // ---- softmax + entropy (all lanes redundantly) ----
  float lmax = psum[0];
#pragma unroll
  for (int t = 1; t < 16; ++t) lmax = fmaxf(lmax, psum[t]);
  float e[16], ssum = 0.f;
#pragma unroll
  for (int t = 0; t < 16; ++t) {
    e[t] = expf((psum[t] - lmax) * (1.0f / 256.0f));
    ssum += e[t];
  }
  float inv = 1.0f / ssum;
  float H = 0.f;
#pragma unroll
  for (int t = 0; t < 16; ++t) {
    float d = e[t] * inv;
    H -= d * logf(fmaxf(d, 1e-8f));
  }
  float conf = 1.0f - H * (1.0f / 2.7725887222397811f);
  conf = fminf(fmaxf(conf, 0.f), 1.f);

  // ---- stage dist to LDS for coalesced output ----
  int l32 = tid & 31, win8 = tid >> 5;
  if (l32 < 16) {
    float dv = e[0];
#pragma unroll
    for (int t = 1; t < 16; ++t) dv = (l32 == t) ? e[t] : dv;
    ldsB[1024 + win8 * 16 + l32] = dv * inv;
  }
  if (l32 == 16) ldsB[1152 + win8] = conf;
  __syncthreads();

  if (tid < 128) {
    int t = tid >> 3, win = tid & 7;
    int wx = wxg * 8 + win;
    out[((size_t)(b * NT + t) * HG + hy) * WG + wx] = ldsB[1024 + win * 16 + t];
  } else if (tid < 136) {
    int win = tid - 128;
    int wx = wxg * 8 + win;
    out[(size_t)NB * NT * HG * WG + ((size_t)b * HG + hy) * WG + wx] =
        ldsB[1152 + win];
  }
}

extern "C" void kernel_launch(void* const* d_in, const int* in_sizes, int n_in,
                              void* d_out, int out_size, void* d_ws,
                              size_t ws_size, hipStream_t stream) {
  (void)in_sizes; (void)n_in; (void)d_ws; (void)ws_size; (void)out_size;
  const float* x = (const float*)d_in[0];
  const float* Wp = (const float*)d_in[1];
  const float* bp = (const float*)d_in[2];
  float* out = (float*)d_out;
  lpp_kernel<<<NB * HG * 6, 256, 0, stream>>>(x, Wp, bp, out);
}